// Round 7
// baseline (304.470 us; speedup 1.0000x reference)
//
#include <hip/hip_runtime.h>
#include <stdint.h>

typedef unsigned short u16;
typedef unsigned int   u32;
typedef short v8s __attribute__((ext_vector_type(8)));   // 8 bf16 = 4 VGPR (MFMA A/B frag)
typedef float v4f __attribute__((ext_vector_type(4)));   // MFMA C/D frag

#define HW   16384      // 128*128
#define NPIX 131072     // 8 * HW
#define WST  264        // Wlds row stride (bf16 elems; 528B rows, 16B aligned)
#define DST  266        // Dlds row stride (f32; 266%32=10 -> <=2-way banks on D store)

__device__ __forceinline__ float sigm(float x) { return 1.f / (1.f + __expf(-x)); }
__device__ __forceinline__ u16 f2bf(float f) {
    u32 u = __float_as_uint(f);
    return (u16)((u + 0x7fffu + ((u >> 16) & 1u)) >> 16);   // RNE
}
__device__ __forceinline__ u32 pk2bf(float a, float b) {    // pack 2 f32 -> 2 bf16 (RNE)
    u32 ua = __float_as_uint(a), ub = __float_as_uint(b);
    u32 ra = (ua + 0x7fffu + ((ua >> 16) & 1u)) >> 16;
    u32 rb = (ub + 0x7fffu + ((ub >> 16) & 1u)) & 0xffff0000u;
    return ra | rb;
}

// R5: LDS-broadcast weights -> LDS-return-BW bound (132us). R6: readlane+FMA ->
// 2 VALU/MAC issue-bound (99us, VALUBusy 57%). R7: the 22x256x131072 matvec is
// a GEMM -> bf16 MFMA (16x16x32). W staged once as bf16 in LDS (22 rows + zero
// pad to 32); each wave: 2 M-tiles x 4 N-tiles(16px) over 8 K-steps, B loads
// double-buffered from global f32 + cvt/pack; f32 accumulate. D -> LDS -> tail
// (R6-verbatim, correctness-proven) runs 1 px/thread.
__global__ __launch_bounds__(256) void half_graph_fused(
    const float* __restrict__ hf,  const float* __restrict__ xhu, const float* __restrict__ xhl,
    const float* __restrict__ xfg, const float* __restrict__ xpg,
    const float* __restrict__ pdp_w1, const float* __restrict__ pdp_w2,
    const float* __restrict__ att_w,  const float* __restrict__ att_b,
    const float* __restrict__ cU_aw, const float* __restrict__ cU_ab, const float* __restrict__ cU_w,
    const float* __restrict__ cL_aw, const float* __restrict__ cL_ab, const float* __restrict__ cL_w,
    const float* __restrict__ dU_aw, const float* __restrict__ dU_ab, const float* __restrict__ dU_w,
    const float* __restrict__ dL_aw, const float* __restrict__ dL_ab, const float* __restrict__ dL_w,
    const float* __restrict__ uU_gw, const float* __restrict__ uU_gb, const float* __restrict__ uU_cw,
    const float* __restrict__ uL_gw, const float* __restrict__ uL_gb, const float* __restrict__ uL_cw,
    float* __restrict__ out)
{
    __shared__ u16   Wlds[32 * WST];   // bf16 W rows 0..21 (+zero pad 22..31)
    __shared__ float Dlds[22 * DST];   // matvec result [o][px_local]

    const int tid = threadIdx.x;
    const int blk = blockIdx.x;
    const int n   = blk >> 6;             // 64 blocks per image (256 px each)
    const int hwb = (blk & 63) * 256;     // block's spatial base

    // ---- stage 22 weight rows as bf16 (rows 0..19 pdp_w1, 20 dU_aw, 21 dL_aw) ----
    for (int i = tid; i < 32 * 256; i += 256) {
        int o = i >> 8, c = i & 255;
        float w = 0.f;
        if (o < 20)       w = pdp_w1[o * 276 + c];
        else if (o == 20) w = dU_aw[c];
        else if (o == 21) w = dL_aw[c];
        Wlds[o * WST + c] = f2bf(w);
    }
    __syncthreads();

    // ---- MFMA GEMM: D[32pad][256px] = W[32][256] * X[256][256px] ----
    const int wv  = tid >> 6;             // wave 0..3 -> px [wv*64, wv*64+64)
    const int ln  = tid & 63;
    const int q   = ln >> 4;              // quad
    const int col = ln & 15;              // A: m-row sub-index; B/D: px column
    const float* xb = hf + (size_t)n * 256 * HW + hwb + wv * 64 + col;

    v4f acc[2][4];
    #pragma unroll
    for (int mt = 0; mt < 2; ++mt)
        #pragma unroll
        for (int t = 0; t < 4; ++t) acc[mt][t] = (v4f){0.f, 0.f, 0.f, 0.f};

    float xr[2][4][8];                    // [buf][ntile][j] raw f32 B elements
    #define ISSUE(buf, k0)                                                   \
        {   _Pragma("unroll")                                                \
            for (int t = 0; t < 4; ++t) {                                    \
                _Pragma("unroll")                                            \
                for (int j = 0; j < 8; ++j)                                  \
                    xr[buf][t][j] = xb[(size_t)((k0) + q * 8 + j) * HW + t * 16]; \
            } }

    ISSUE(0, 0)
    #pragma unroll
    for (int ks = 0; ks < 8; ++ks) {
        if (ks < 7) ISSUE((ks + 1) & 1, (ks + 1) * 32)
        // A frags: lane ln -> W[mt*16 + col][ks*32 + q*8 + j], j=0..7 (16B LDS read)
        v8s a0 = *(const v8s*)&Wlds[(col) * WST + ks * 32 + q * 8];
        v8s a1 = *(const v8s*)&Wlds[(16 + col) * WST + ks * 32 + q * 8];
        const int buf = ks & 1;
        #pragma unroll
        for (int t = 0; t < 4; ++t) {
            union { u32 w[4]; v8s v; } bf;
            #pragma unroll
            for (int i = 0; i < 4; ++i)
                bf.w[i] = pk2bf(xr[buf][t][2 * i], xr[buf][t][2 * i + 1]);
            acc[0][t] = __builtin_amdgcn_mfma_f32_16x16x32_bf16(a0, bf.v, acc[0][t], 0, 0, 0);
            acc[1][t] = __builtin_amdgcn_mfma_f32_16x16x32_bf16(a1, bf.v, acc[1][t], 0, 0, 0);
        }
    }
    #undef ISSUE

    // ---- D -> LDS: lane holds rows mt*16 + q*4 + r, cols wv*64 + t*16 + col ----
    #pragma unroll
    for (int mt = 0; mt < 2; ++mt)
        #pragma unroll
        for (int r = 0; r < 4; ++r) {
            int o = mt * 16 + q * 4 + r;
            if (o < 22) {
                #pragma unroll
                for (int t = 0; t < 4; ++t)
                    Dlds[o * DST + wv * 64 + t * 16 + col] = acc[mt][t][r];
            }
        }
    __syncthreads();

    // ================= tail: 1 px/thread (R6-verbatim) =================
    const int p  = blk * 256 + tid;
    const int hw = p & 16383;

    float accT[20];
    #pragma unroll
    for (int o = 0; o < 20; ++o) accT[o] = Dlds[o * DST + tid];
    const float dU = Dlds[20 * DST + tid], dL = Dlds[21 * DST + tid];

    float xu[10], xl[10], xv[10];
    {
        const float* a = xhu + (size_t)n * 10 * HW + hw;
        const float* b = xhl + (size_t)n * 10 * HW + hw;
        const float* c = xfg + (size_t)n * 10 * HW + hw;
        #pragma unroll
        for (int i = 0; i < 10; ++i) xu[i] = a[i * HW];
        #pragma unroll
        for (int i = 0; i < 10; ++i) xl[i] = b[i * HW];
        #pragma unroll
        for (int i = 0; i < 10; ++i) xv[i] = c[i * HW];
    }

    // pdp: t = relu(W1 @ [hf,xu,xl])
    float t[20];
    #pragma unroll
    for (int o = 0; o < 20; ++o) {
        float s = accT[o];
        #pragma unroll
        for (int i = 0; i < 10; ++i) s = fmaf(pdp_w1[o * 276 + 256 + i], xu[i], s);
        #pragma unroll
        for (int i = 0; i < 10; ++i) s = fmaf(pdp_w1[o * 276 + 266 + i], xl[i], s);
        t[o] = fmaxf(s, 0.f);
    }
    float dpv[20];
    #pragma unroll
    for (int g = 0; g < 2; ++g) {
        #pragma unroll
        for (int o = 0; o < 10; ++o) {
            float s = 0.f;
            #pragma unroll
            for (int i = 0; i < 10; ++i)
                s = fmaf(pdp_w2[(g * 10 + o) * 10 + i], t[g * 10 + i], s);
            dpv[g * 10 + o] = fmaxf(s, 0.f);
        }
    }

    float au_s = att_b[0], al_s = att_b[1];
    #pragma unroll
    for (int i = 0; i < 10; ++i) {
        au_s = fmaf(att_w[i], xu[i], au_s);
        al_s = fmaf(att_w[10 + i], xl[i], al_s);
    }
    const float au = sigm(au_s), al = sigm(al_s);

    float su = dU + dU_ab[0];
    float sl = dL + dL_ab[0];
    #pragma unroll
    for (int i = 0; i < 10; ++i) { su = fmaf(dU_aw[256 + i], xv[i], su); sl = fmaf(dL_aw[256 + i], xv[i], sl); }
    #pragma unroll
    for (int i = 0; i < 10; ++i) { su = fmaf(dU_aw[266 + i], xu[i], su); sl = fmaf(dL_aw[266 + i], xl[i], sl); }
    const float attU = sigm(su), attL = sigm(sl);

    float xfhu[10], xfhl[10];
    #pragma unroll
    for (int o = 0; o < 10; ++o) {
        float a = 0.f, b = 0.f;
        #pragma unroll
        for (int i = 0; i < 10; ++i) {
            a = fmaf(dU_w[o * 10 + i], xv[i], a);
            b = fmaf(dL_w[o * 10 + i], xv[i], b);
        }
        xfhu[o] = fmaxf(attU * a, 0.f);
        xfhl[o] = fmaxf(attL * b, 0.f);
    }

    float msgU[10];
    #pragma unroll
    for (int i = 0; i < 10; ++i) msgU[i] = 0.f;
    #pragma unroll
    for (int pp = 0; pp < 4; ++pp) {
        const float* xq = xpg + (size_t)(pp * 8 + n) * 10 * HW + hw;
        float v[10];
        #pragma unroll
        for (int i = 0; i < 10; ++i) v[i] = xq[i * HW];
        float s = cU_ab[pp];
        #pragma unroll
        for (int i = 0; i < 10; ++i) s = fmaf(cU_aw[pp * 10 + i], v[i], s);
        float ca = sigm(s);
        #pragma unroll
        for (int i = 0; i < 10; ++i) msgU[i] = fmaf(ca, v[i], msgU[i]);
    }
    float xphu[10];
    #pragma unroll
    for (int o = 0; o < 10; ++o) {
        float s = 0.f;
        #pragma unroll
        for (int i = 0; i < 10; ++i) s = fmaf(cU_w[o * 20 + i], xu[i], s);
        #pragma unroll
        for (int i = 0; i < 10; ++i) s = fmaf(cU_w[o * 20 + 10 + i], msgU[i], s);
        xphu[o] = fmaxf(s, 0.f);
    }

    float msgL[10];
    #pragma unroll
    for (int i = 0; i < 10; ++i) msgL[i] = 0.f;
    #pragma unroll
    for (int pp = 4; pp < 6; ++pp) {
        const float* xq = xpg + (size_t)(pp * 8 + n) * 10 * HW + hw;
        float v[10];
        #pragma unroll
        for (int i = 0; i < 10; ++i) v[i] = xq[i * HW];
        float s = cL_ab[pp - 4];
        #pragma unroll
        for (int i = 0; i < 10; ++i) s = fmaf(cL_aw[(pp - 4) * 10 + i], v[i], s);
        float ca = sigm(s);
        #pragma unroll
        for (int i = 0; i < 10; ++i) msgL[i] = fmaf(ca, v[i], msgL[i]);
    }
    float xphl[10];
    #pragma unroll
    for (int o = 0; o < 10; ++o) {
        float s = 0.f;
        #pragma unroll
        for (int i = 0; i < 10; ++i) s = fmaf(cL_w[o * 20 + i], xl[i], s);
        #pragma unroll
        for (int i = 0; i < 10; ++i) s = fmaf(cL_w[o * 20 + 10 + i], msgL[i], s);
        xphl[o] = fmaxf(s, 0.f);
    }

    float outU[10], outL[10];
    {
        float m[10];
        #pragma unroll
        for (int i = 0; i < 10; ++i)
            m[i] = xphu[i] + (dpv[10 + i] * al + xu[i] * au) + xfhu[i];  // xlh
        #pragma unroll
        for (int o = 0; o < 10; ++o) {
            float gs = uU_gb[o], cs = 0.f;
            #pragma unroll
            for (int i = 0; i < 10; ++i) {
                gs = fmaf(uU_gw[o * 20 + i], xu[i], gs);
                cs = fmaf(uU_cw[o * 20 + i], xu[i], cs);
            }
            #pragma unroll
            for (int i = 0; i < 10; ++i) {
                gs = fmaf(uU_gw[o * 20 + 10 + i], m[i], gs);
                cs = fmaf(uU_cw[o * 20 + 10 + i], m[i], cs);
            }
            float g = sigm(gs), cd = fmaxf(cs, 0.f);
            outU[o] = xu[o] * (1.f - g) + cd * g;
        }
    }
    {
        float m[10];
        #pragma unroll
        for (int i = 0; i < 10; ++i)
            m[i] = xphl[i] + (dpv[i] * au + xl[i] * al) + xfhl[i];       // xuh
        #pragma unroll
        for (int o = 0; o < 10; ++o) {
            float gs = uL_gb[o], cs = 0.f;
            #pragma unroll
            for (int i = 0; i < 10; ++i) {
                gs = fmaf(uL_gw[o * 20 + i], xl[i], gs);
                cs = fmaf(uL_cw[o * 20 + i], xl[i], cs);
            }
            #pragma unroll
            for (int i = 0; i < 10; ++i) {
                gs = fmaf(uL_gw[o * 20 + 10 + i], m[i], gs);
                cs = fmaf(uL_cw[o * 20 + 10 + i], m[i], cs);
            }
            float g = sigm(gs), cd = fmaxf(cs, 0.f);
            outL[o] = xl[o] * (1.f - g) + cd * g;
        }
    }

    {
        int baseU = n * 10 * HW + hw;
        #pragma unroll
        for (int c = 0; c < 10; ++c) out[baseU + c * HW] = outU[c];
        int baseL = 1310720 + baseU;
        #pragma unroll
        for (int c = 0; c < 10; ++c) out[baseL + c * HW] = outL[c];
        out[2621440 + n * HW + hw] = attU;
        out[2752512 + n * HW + hw] = attL;
    }
}

extern "C" void kernel_launch(void* const* d_in, const int* in_sizes, int n_in,
                              void* d_out, int out_size, void* d_ws, size_t ws_size,
                              hipStream_t stream) {
    (void)in_sizes; (void)n_in; (void)out_size; (void)d_ws; (void)ws_size;
    const float* hf   = (const float*)d_in[0];
    const float* xhu  = (const float*)d_in[1];
    const float* xhl  = (const float*)d_in[2];
    const float* xfg  = (const float*)d_in[3];
    const float* xpg  = (const float*)d_in[4];
    const float* w1   = (const float*)d_in[5];
    const float* w2   = (const float*)d_in[6];
    const float* aw   = (const float*)d_in[7];
    const float* ab   = (const float*)d_in[8];
    const float* cUaw = (const float*)d_in[9];
    const float* cUab = (const float*)d_in[10];
    const float* cUw  = (const float*)d_in[11];
    const float* cLaw = (const float*)d_in[12];
    const float* cLab = (const float*)d_in[13];
    const float* cLw  = (const float*)d_in[14];
    const float* dUaw = (const float*)d_in[15];
    const float* dUab = (const float*)d_in[16];
    const float* dUw  = (const float*)d_in[17];
    const float* dLaw = (const float*)d_in[18];
    const float* dLab = (const float*)d_in[19];
    const float* dLw  = (const float*)d_in[20];
    const float* uUgw = (const float*)d_in[21];
    const float* uUgb = (const float*)d_in[22];
    const float* uUcw = (const float*)d_in[23];
    const float* uLgw = (const float*)d_in[24];
    const float* uLgb = (const float*)d_in[25];
    const float* uLcw = (const float*)d_in[26];

    dim3 grid(NPIX / 256), block(256);   // 256 px per block (4 waves x 64 px)
    hipLaunchKernelGGL(half_graph_fused, grid, block, 0, stream,
        hf, xhu, xhl, xfg, xpg, w1, w2, aw, ab,
        cUaw, cUab, cUw, cLaw, cLab, cLw,
        dUaw, dUab, dUw, dLaw, dLab, dLw,
        uUgw, uUgb, uUcw, uLgw, uLgb, uLcw,
        (float*)d_out);
}